// Round 16
// baseline (296.153 us; speedup 1.0000x reference)
//
#include <hip/hip_runtime.h>

typedef __bf16 bf16x8 __attribute__((ext_vector_type(8)));
typedef float f32x4 __attribute__((ext_vector_type(4)));

__device__ __forceinline__ ushort f2b(float f){
  union { float f; unsigned u; } v; v.f = f;
  unsigned r = v.u + 0x7FFFu + ((v.u >> 16) & 1u);
  return (ushort)(r >> 16);
}
__device__ __forceinline__ float b2f(ushort b){
  union { unsigned u; float f; } v; v.u = ((unsigned)b) << 16; return v.f;
}

__device__ __forceinline__ void gload16(const ushort* g, ushort* lds){
  __builtin_amdgcn_global_load_lds(
      (const __attribute__((address_space(1))) unsigned int*)(g),
      (__attribute__((address_space(3))) unsigned int*)(lds), 16, 0, 0);
}

#define VMW(n)  do { asm volatile("s_waitcnt vmcnt(" #n ")" ::: "memory"); __builtin_amdgcn_sched_barrier(0); } while(0)
#define BARR    do { __builtin_amdgcn_s_barrier(); __builtin_amdgcn_sched_barrier(0); } while(0)

// ============ prep mega-kernel: hs cvt | enc cvt | 6 weight transposes | T_ip ============
__global__ __launch_bounds__(256) void prep_k(
    const float* __restrict__ hs, const float* __restrict__ enc,
    const float* __restrict__ Wq, const float* __restrict__ Wout,
    const float* __restrict__ Wk, const float* __restrict__ Wv,
    const float* __restrict__ Wkip, const float* __restrict__ Wvip,
    ushort* __restrict__ hs_bf, ushort* __restrict__ enc_bf,
    ushort* __restrict__ wqt, ushort* __restrict__ woutt, ushort* __restrict__ wcat,
    float* __restrict__ tip)
{
  __shared__ float tile[32][33];
  int bid = blockIdx.x;
  int t = threadIdx.x;

  if (bid < 20480){                       // hs f32 -> bf16
    int i = bid*256 + t;
    f32x4 v = reinterpret_cast<const f32x4*>(hs)[i];
    ushort4 o = make_ushort4(f2b(v.x), f2b(v.y), f2b(v.z), f2b(v.w));
    reinterpret_cast<ushort4*>(hs_bf)[i] = o;
    return;
  }
  bid -= 20480;
  if (bid < 768){                         // enc f32 -> bf16 (pad to 384 rows)
    int i = bid*256 + t;
    f32x4 v = {0.f,0.f,0.f,0.f};
    if (i < 324*2048/4) v = reinterpret_cast<const f32x4*>(enc)[i];
    ushort4 o = make_ushort4(f2b(v.x), f2b(v.y), f2b(v.z), f2b(v.w));
    reinterpret_cast<ushort4*>(enc_bf)[i] = o;
    return;
  }
  bid -= 768;
  if (bid < 13440){                       // weight transposes
    const float* Wsrc; ushort* Wdst; int K;
    if (bid < 1600)      { Wsrc = Wq;   Wdst = wqt;                    K = 1280; }
    else if (bid < 3200) { bid -= 1600; Wsrc = Wout; Wdst = woutt;     K = 1280; }
    else if (bid < 5760) { bid -= 3200; Wsrc = Wk;   Wdst = wcat;      K = 2048; }
    else if (bid < 8320) { bid -= 5760; Wsrc = Wv;   Wdst = wcat + 1ull*1280*2048; K = 2048; }
    else if (bid < 10880){ bid -= 8320; Wsrc = Wkip; Wdst = wcat + 2ull*1280*2048; K = 2048; }
    else                 { bid -= 10880; Wsrc = Wvip; Wdst = wcat + 3ull*1280*2048; K = 2048; }
    int n0 = (bid % 40)*32, k0 = (bid / 40)*32;
    int tx = t & 31, ty = t >> 5;
    for (int i = ty; i < 32; i += 8) tile[i][tx] = Wsrc[(size_t)(k0+i)*1280 + n0+tx];
    __syncthreads();
    for (int i = ty; i < 32; i += 8) Wdst[(size_t)(n0+i)*K + k0+tx] = f2b(tile[tx][i]);
    return;
  }
  bid -= 13440;
  {                                       // tip[b][k][n] = 0.125 * text[b,k]·ip[b,n]
    int b = bid / 77, k = bid % 77;
    int n = t >> 6, l = t & 63;
    const float* text = enc + ((size_t)b*81 + k)*2048;
    const float* ip   = enc + ((size_t)b*81 + 77 + n)*2048;
    float acc = 0.f;
    for (int c = l; c < 2048; c += 64) acc += text[c]*ip[c];
    #pragma unroll
    for (int off = 32; off > 0; off >>= 1) acc += __shfl_xor(acc, off);
    if (l == 0) tip[((size_t)b*77 + k)*4 + n] = acc * 0.125f;
  }
}

// ============ shared 128x128 GEMM body: BK=32, 3-buffer counted-vmcnt pipeline ============
// R7's 68-VGPR variant: per K-step = VMW(4); barrier; stage(kt+2); ds_read; 16 MFMA/wave.
// Loads stay in flight across barriers. 48KB LDS -> 3 blocks/CU.
// `#pragma unroll 1` — K is compile-time const here; full unroll costs +24 VGPR (R9/R10).
// MODE 1 epilogue uses nontemporal resid-load + out-store (both touched exactly once).
template<int MODE>
__device__ __forceinline__ void gemm_body(
    const ushort* __restrict__ A, const ushort* __restrict__ Bt,
    int K, int lda, int ldb, int ldo,
    float* __restrict__ outF, ushort* __restrict__ outB,
    const float* __restrict__ bias, const float* __restrict__ resid,
    int mt, int nt)
{
  __shared__ ushort As[3][128*32];
  __shared__ ushort Bs[3][128*32];
  int t = threadIdx.x;
  int w = t >> 6, l = t & 63;
  int wr = w >> 1, wc = w & 1;
  int fr = l & 15, fq = l >> 4;

  int r0 = t >> 2, s0 = t & 3;
  int r1 = r0 + 64;
  int sc0 = ((s0 ^ ((r0 >> 1) & 3)) << 3);
  int sc1 = ((s0 ^ ((r1 >> 1) & 3)) << 3);
  const ushort* Ag0 = A  + (size_t)(mt*128 + r0)*lda + sc0;
  const ushort* Ag1 = A  + (size_t)(mt*128 + r1)*lda + sc1;
  const ushort* Bg0 = Bt + (size_t)(nt*128 + r0)*ldb + sc0;
  const ushort* Bg1 = Bt + (size_t)(nt*128 + r1)*ldb + sc1;

  f32x4 acc[4][4];
  #pragma unroll
  for (int m = 0; m < 4; ++m)
    #pragma unroll
    for (int n = 0; n < 4; ++n) acc[m][n] = (f32x4){0.f,0.f,0.f,0.f};

  auto stage = [&](int s, int kt){
    int ko = kt << 5;
    ushort* a = &As[s][0] + t*8;
    ushort* b = &Bs[s][0] + t*8;
    gload16(Ag0 + ko, a);
    gload16(Ag1 + ko, a + 2048);
    gload16(Bg0 + ko, b);
    gload16(Bg1 + ko, b + 2048);
  };
  auto compute = [&](int s){
    bf16x8 af[4], bf[4];
    #pragma unroll
    for (int m = 0; m < 4; ++m){
      int row = wr*64 + m*16 + fr;
      af[m] = *reinterpret_cast<const bf16x8*>(&As[s][row*32 + ((fq ^ ((row >> 1) & 3)) << 3)]);
    }
    #pragma unroll
    for (int n = 0; n < 4; ++n){
      int row = wc*64 + n*16 + fr;
      bf[n] = *reinterpret_cast<const bf16x8*>(&Bs[s][row*32 + ((fq ^ ((row >> 1) & 3)) << 3)]);
    }
    #pragma unroll
    for (int m = 0; m < 4; ++m)
      #pragma unroll
      for (int n = 0; n < 4; ++n)
        acc[m][n] = __builtin_amdgcn_mfma_f32_16x16x32_bf16(af[m], bf[n], acc[m][n], 0, 0, 0);
  };

  int nk = K >> 5;
  stage(0, 0);
  stage(1, 1);
  int kt = 0;
  #pragma unroll 1
  for (; kt < nk - 1; ++kt){
    VMW(4);                 // tile kt landed (only stage(kt+1) may be in flight)
    BARR;
    if (kt + 2 < nk) stage((kt + 2) % 3, kt + 2);
    compute(kt % 3);
  }
  VMW(0);
  BARR;
  compute(kt % 3);

  int fqb = fq << 2;
  #pragma unroll
  for (int m = 0; m < 4; ++m){
    #pragma unroll
    for (int n = 0; n < 4; ++n){
      #pragma unroll
      for (int r = 0; r < 4; ++r){
        int row = mt*128 + wr*64 + m*16 + fqb + r;
        int col = nt*128 + wc*64 + n*16 + fr;
        size_t oidx = (size_t)row*ldo + col;
        float v = acc[m][n][r];
        if (MODE == 0){
          outB[oidx] = f2b(v);
        } else {
          float rv = __builtin_nontemporal_load(&resid[oidx]);
          __builtin_nontemporal_store(v + bias[col] + rv, &outF[oidx]);
        }
      }
    }
  }
}

// enc-proj (K=2048, longer blocks) on blockIdx 0..119 so they launch FIRST and run
// in q-proj's shadow; q-proj swizzled bijectively over its own 1280 range.
__global__ __launch_bounds__(256) void gemm_dual_k(
    const ushort* __restrict__ A1, const ushort* __restrict__ B1, ushort* __restrict__ O1,
    const ushort* __restrict__ A2, const ushort* __restrict__ B2, ushort* __restrict__ O2)
{
  int bid = blockIdx.x;
  if (bid < 120){
    gemm_body<0>(A2, B2, 2048, 2048, 2048, 5120,
                 nullptr, O2, nullptr, nullptr, bid/40, bid%40);
  } else {
    int qb = bid - 120;
    qb = (qb & 7)*160 + (qb >> 3);        // 1280/8 = 160, bijective
    gemm_body<0>(A1, B1, 1280, 1280, 1280, 1280,
                 nullptr, O1, nullptr, nullptr, qb/10, qb%10);
  }
}

// out-proj: fp32 + bias + residual
__global__ __launch_bounds__(256) void gemm_out_k(
    const ushort* __restrict__ A, const ushort* __restrict__ Bt, float* __restrict__ outF,
    const float* __restrict__ bias, const float* __restrict__ resid)
{
  int nwg = gridDim.x;
  int bid = blockIdx.x;
  if ((nwg & 7) == 0){
    int cpx = nwg >> 3;
    bid = (bid & 7)*cpx + (bid >> 3);
  }
  gemm_body<1>(A, Bt, 1280, 1280, 1280, 1280,
               outF, nullptr, bias, resid, bid/10, bid%10);
}

// ============ fused logits + text-softmax + sem kernel ============
__global__ __launch_bounds__(256) void logits_sem_k(
    const ushort* __restrict__ q, const ushort* __restrict__ pall,
    const float* __restrict__ tip, float* __restrict__ sem)
{
  __shared__ ushort As[64][40];
  __shared__ ushort Bs[128][40];
  __shared__ float tipS[77][4];
  int mt = blockIdx.x;
  int z  = blockIdx.z;
  int t = threadIdx.x;
  const ushort* Ab = q + (size_t)z*4096*1280;
  const ushort* Bb = pall + (size_t)z*81*5120;
  for (int i = t; i < 308; i += 256) (&tipS[0][0])[i] = tip[(size_t)z*308 + i];

  int w = t >> 6, l = t & 63;
  int fr = l & 15, fq = l >> 4, fk = fq << 3;
  int alr = t >> 2, alc = (t & 3) << 3;

  const ushort* Aptr  = Ab + (size_t)(mt*64 + alr)*1280 + alc;
  const ushort* Bptr0 = Bb + (size_t)alr*5120 + alc;
  const ushort* Bptr1 = Bb + (size_t)(64 + alr)*5120 + alc;

  f32x4 acc[5];
  #pragma unroll
  for (int n = 0; n < 5; ++n) acc[n] = (f32x4){0.f,0.f,0.f,0.f};

  uint4 a0 = *reinterpret_cast<const uint4*>(Aptr);
  uint4 b0 = *reinterpret_cast<const uint4*>(Bptr0);
  uint4 b1 = *reinterpret_cast<const uint4*>(Bptr1);
  #pragma unroll 1
  for (int k0 = 0; k0 < 1280; k0 += 32){
    __syncthreads();
    *reinterpret_cast<uint4*>(&As[alr][alc]) = a0;
    *reinterpret_cast<uint4*>(&Bs[alr][alc]) = b0;
    *reinterpret_cast<uint4*>(&Bs[64+alr][alc]) = b1;
    if (k0 + 32 < 1280){
      a0 = *reinterpret_cast<const uint4*>(Aptr + k0 + 32);
      b0 = *reinterpret_cast<const uint4*>(Bptr0 + k0 + 32);
      b1 = *reinterpret_cast<const uint4*>(Bptr1 + k0 + 32);
    }
    __syncthreads();
    bf16x8 af = *reinterpret_cast<const bf16x8*>(&As[w*16 + fr][fk]);
    #pragma unroll
    for (int n = 0; n < 5; ++n){
      bf16x8 bf = *reinterpret_cast<const bf16x8*>(&Bs[n*16 + fr][fk]);
      acc[n] = __builtin_amdgcn_mfma_f32_16x16x32_bf16(af, bf, acc[n], 0, 0, 0);
    }
  }

  bool v4 = (fr < 13);     // col 64+fr < 77
  #pragma unroll
  for (int r = 0; r < 4; ++r){
    float lg[5];
    #pragma unroll
    for (int n = 0; n < 5; ++n) lg[n] = acc[n][r]*0.125f;
    float m = fmaxf(fmaxf(lg[0],lg[1]), fmaxf(lg[2],lg[3]));
    if (v4) m = fmaxf(m, lg[4]);
    #pragma unroll
    for (int off = 1; off < 16; off <<= 1) m = fmaxf(m, __shfl_xor(m, off));
    float s = __expf(lg[0]-m) + __expf(lg[1]-m) + __expf(lg[2]-m) + __expf(lg[3]-m);
    if (v4) s += __expf(lg[4]-m);
    #pragma unroll
    for (int off = 1; off < 16; off <<= 1) s += __shfl_xor(s, off);
    float inv = 1.f / s;
    float a0s = 0.f, a1s = 0.f, a2s = 0.f, a3s = 0.f;
    #pragma unroll
    for (int n = 0; n < 5; ++n){
      int c = n*16 + fr;
      if (n < 4 || v4){
        float p = __expf(lg[n]-m) * inv;
        a0s += p*tipS[c][0]; a1s += p*tipS[c][1];
        a2s += p*tipS[c][2]; a3s += p*tipS[c][3];
      }
    }
    #pragma unroll
    for (int off = 1; off < 16; off <<= 1){
      a0s += __shfl_xor(a0s, off); a1s += __shfl_xor(a1s, off);
      a2s += __shfl_xor(a2s, off); a3s += __shfl_xor(a3s, off);
    }
    if (fr == 0){
      size_t row = (size_t)z*4096 + mt*64 + w*16 + fq*4 + r;
      f32x4 o = {a0s, a1s, a2s, a3s};
      *reinterpret_cast<f32x4*>(&sem[row*4]) = o;
    }
  }
}

// ============ MFMA fused text+ip attention: 4 q-tiles per block ============
// K/V/Vt staged once, amortized over four 64-row Q-tiles. Barrier safety:
// Qs rewrite occurs after the post-Ps barrier (all QK^T reads done); Ps rewrite
// occurs after the pre-QK^T barrier (all prev-PV reads done) — same as the
// verified 2-tile R13 structure.
__global__ __launch_bounds__(256) void attn_mfma_k(
    const ushort* __restrict__ qb, const ushort* __restrict__ pall,
    const float* __restrict__ sem, const float* __restrict__ mask,
    ushort* __restrict__ hmid)
{
  int qp = blockIdx.x;   // 0..15 (quad of q-tiles)
  int h  = blockIdx.y;   // 0..19
  int b  = blockIdx.z;   // 0..3
  __shared__ ushort Qs[64][72];
  __shared__ ushort Ks[96][72];
  __shared__ ushort Vt[64][104];  // V^T: [d][k]
  __shared__ ushort Ps[64][104];
  int t = threadIdx.x;
  int w = t >> 6, l = t & 63;
  const ushort* pb = pall + (size_t)b*81*5120 + h*64;

  // stage K rows (text 0..76, ip 77..80, zero 81..95)
  #pragma unroll
  for (int it = 0; it < 6; ++it){
    int chunk = t + it*256;
    int k = chunk >> 4, dp = (chunk & 15) << 2;
    ushort4 v = make_ushort4(0,0,0,0);
    if (k < 77)      v = *reinterpret_cast<const ushort4*>(pb + (size_t)k*5120 + dp);
    else if (k < 81) v = *reinterpret_cast<const ushort4*>(pb + (size_t)k*5120 + 2560 + dp);
    *reinterpret_cast<ushort4*>(&Ks[k][dp]) = v;
  }
  // V^T staging (ushort4): rows 81..95 are finite garbage x zero P cols
  #pragma unroll
  for (int it = 0; it < 6; ++it){
    int idx = t + it*256;
    int k = idx >> 4, d4 = (idx & 15) << 2;
    const ushort* src = (k < 77) ? pb + (size_t)k*5120 + 1280 + d4
                                 : pb + (size_t)k*5120 + 3840 + d4;
    ushort4 v = *reinterpret_cast<const ushort4*>(src);
    Vt[d4][k] = v.x; Vt[d4+1][k] = v.y; Vt[d4+2][k] = v.z; Vt[d4+3][k] = v.w;
  }

  int fr = l & 15, fq = l >> 4, fkb = fq << 3;
  int c = fr;

  #pragma unroll 1
  for (int half = 0; half < 4; ++half){
    int qt = qp*4 + half;
    {
      int base = b*4096 + qt*64;
      #pragma unroll
      for (int it = 0; it < 2; ++it){
        int chunk = t + it*256;
        int r = chunk >> 3, dp = (chunk & 7) << 3;
        uint4 v = *reinterpret_cast<const uint4*>(qb + (size_t)(base + r)*1280 + h*64 + dp);
        *reinterpret_cast<uint4*>(&Qs[r][dp]) = v;
      }
    }
    __syncthreads();   // Q (and on half 0: K/V) staged; guards prev-half PV reads of Ps

    f32x4 s[6];
    #pragma unroll
    for (int n = 0; n < 6; ++n) s[n] = (f32x4){0.f,0.f,0.f,0.f};
    #pragma unroll
    for (int ks = 0; ks < 2; ++ks){
      bf16x8 aq = *reinterpret_cast<const bf16x8*>(&Qs[w*16 + fr][ks*32 + fkb]);
      #pragma unroll
      for (int n = 0; n < 6; ++n){
        bf16x8 bk = *reinterpret_cast<const bf16x8*>(&Ks[n*16 + fr][ks*32 + fkb]);
        s[n] = __builtin_amdgcn_mfma_f32_16x16x32_bf16(aq, bk, s[n], 0, 0, 0);
      }
    }

    int rowbase = qt*64 + w*16 + (fq << 2);
    #pragma unroll
    for (int r = 0; r < 4; ++r){
      float lg[6];
      #pragma unroll
      for (int n = 0; n < 6; ++n) lg[n] = s[n][r]*0.125f;

      float mt = fmaxf(fmaxf(lg[0],lg[1]), fmaxf(lg[2],lg[3]));
      if (c < 13) mt = fmaxf(mt, lg[4]);
      #pragma unroll
      for (int off = 1; off < 16; off <<= 1) mt = fmaxf(mt, __shfl_xor(mt, off));
      float st = __expf(lg[0]-mt) + __expf(lg[1]-mt) + __expf(lg[2]-mt) + __expf(lg[3]-mt);
      if (c < 13) st += __expf(lg[4]-mt);
      #pragma unroll
      for (int off = 1; off < 16; off <<= 1) st += __shfl_xor(st, off);
      float invst = 1.f/st;

      size_t qrow = (size_t)b*4096 + rowbase + r;
      float f4 = -1e30f, f5 = -1e30f;
      if (c >= 13) f4 = lg[4] + 0.5f*sem[qrow*4 + (c-13)];
      if (c == 0)  f5 = lg[5] + 0.5f*sem[qrow*4 + 3];
      float m2 = fmaxf(f4, f5);
      #pragma unroll
      for (int off = 1; off < 16; off <<= 1) m2 = fmaxf(m2, __shfl_xor(m2, off));
      float si = (c >= 13 ? __expf(f4-m2) : 0.f) + (c == 0 ? __expf(f5-m2) : 0.f);
      #pragma unroll
      for (int off = 1; off < 16; off <<= 1) si += __shfl_xor(si, off);
      float pmul = mask[rowbase + r] / si;

      int prow = w*16 + (fq << 2) + r;
      #pragma unroll
      for (int n = 0; n < 4; ++n) Ps[prow][n*16 + c] = f2b(__expf(lg[n]-mt)*invst);
      Ps[prow][64 + c] = f2b(c < 13 ? __expf(lg[4]-mt)*invst : __expf(f4-m2)*pmul);
      Ps[prow][80 + c] = f2b(c == 0 ? __expf(f5-m2)*pmul : 0.f);
    }
    __syncthreads();   // Ps complete before PV

    f32x4 o[4];
    #pragma unroll
    for (int df = 0; df < 4; ++df) o[df] = (f32x4){0.f,0.f,0.f,0.f};
    #pragma unroll
    for (int ks = 0; ks < 3; ++ks){
      bf16x8 ap = *reinterpret_cast<const bf16x8*>(&Ps[w*16 + fr][ks*32 + fkb]);
      #pragma unroll
      for (int df = 0; df < 4; ++df){
        bf16x8 bv = *reinterpret_cast<const bf16x8*>(&Vt[df*16 + fr][ks*32 + fkb]);
        o[df] = __builtin_amdgcn_mfma_f32_16x16x32_bf16(ap, bv, o[df], 0, 0, 0);
      }
    }
    #pragma unroll
    for (int df = 0; df < 4; ++df)
      #pragma unroll
      for (int r = 0; r < 4; ++r)
        hmid[((size_t)b*4096 + rowbase + r)*1280 + h*64 + df*16 + c] = f2b(o[df][r]);
  }
}

extern "C" void kernel_launch(void* const* d_in, const int* in_sizes, int n_in,
                              void* d_out, int out_size, void* d_ws, size_t ws_size,
                              hipStream_t stream)
{
  (void)in_sizes; (void)n_in; (void)out_size; (void)ws_size;
  const float* hs   = (const float*)d_in[0];
  const float* enc  = (const float*)d_in[1];
  const float* mask = (const float*)d_in[2];
  const float* Wq   = (const float*)d_in[3];
  const float* Wk   = (const float*)d_in[4];
  const float* Wv   = (const float*)d_in[5];
  const float* Wkip = (const float*)d_in[6];
  const float* Wvip = (const float*)d_in[7];
  const float* Wout = (const float*)d_in[8];
  const float* bout = (const float*)d_in[9];
  float* out = (float*)d_out;
  char* ws = (char*)d_ws;

  size_t off = 0;
  auto alloc = [&](size_t bytes)->char*{
    char* p = ws + off; off += (bytes + 255) & ~(size_t)255; return p;
  };
  ushort* hs_bf   = (ushort*)alloc(16384ull*1280*2);   // reused as hmid
  ushort* q_bf    = (ushort*)alloc(16384ull*1280*2);
  ushort* enc_bf  = (ushort*)alloc(384ull*2048*2);
  ushort* wqt     = (ushort*)alloc(1280ull*1280*2);
  ushort* woutt   = (ushort*)alloc(1280ull*1280*2);
  ushort* wcat    = (ushort*)alloc(5120ull*2048*2);
  ushort* pall    = (ushort*)alloc(384ull*5120*2);
  float*  tip     = (float*)alloc(4ull*77*4*4);
  float*  semb    = (float*)alloc(16384ull*4*4);
  ushort* hmid_bf = hs_bf;

  // 1) all preprocessing in one launch
  prep_k<<<34996, 256, 0, stream>>>(hs, enc, Wq, Wout, Wk, Wv, Wkip, Wvip,
                                    hs_bf, enc_bf, wqt, woutt, wcat, tip);

  // 2) q-projection + encoder projections in one launch (enc first)
  gemm_dual_k<<<1400, 256, 0, stream>>>(hs_bf, wqt, q_bf, enc_bf, wcat, pall);

  // 3) fused logits + text softmax + sem
  logits_sem_k<<<dim3(64,1,4), 256, 0, stream>>>(q_bf, pall, tip, semb);

  // 4) fused attention -> hmid (bf16)
  attn_mfma_k<<<dim3(16,20,4), 256, 0, stream>>>(q_bf, pall, semb, mask, hmid_bf);

  // 5) out = hmid @ Wout + bout + residual
  gemm_out_k<<<1280, 256, 0, stream>>>(hmid_bf, woutt, out, bout, hs);
}

// Round 17
// 288.779 us; speedup vs baseline: 1.0255x; 1.0255x over previous
//
#include <hip/hip_runtime.h>

typedef __bf16 bf16x8 __attribute__((ext_vector_type(8)));
typedef float f32x4 __attribute__((ext_vector_type(4)));

__device__ __forceinline__ ushort f2b(float f){
  union { float f; unsigned u; } v; v.f = f;
  unsigned r = v.u + 0x7FFFu + ((v.u >> 16) & 1u);
  return (ushort)(r >> 16);
}
__device__ __forceinline__ float b2f(ushort b){
  union { unsigned u; float f; } v; v.u = ((unsigned)b) << 16; return v.f;
}

__device__ __forceinline__ void gload16(const ushort* g, ushort* lds){
  __builtin_amdgcn_global_load_lds(
      (const __attribute__((address_space(1))) unsigned int*)(g),
      (__attribute__((address_space(3))) unsigned int*)(lds), 16, 0, 0);
}

#define VMW(n)  do { asm volatile("s_waitcnt vmcnt(" #n ")" ::: "memory"); __builtin_amdgcn_sched_barrier(0); } while(0)
#define BARR    do { __builtin_amdgcn_s_barrier(); __builtin_amdgcn_sched_barrier(0); } while(0)

// ============ prep mega-kernel: hs cvt | enc cvt | 6 weight transposes | T_ip ============
__global__ __launch_bounds__(256) void prep_k(
    const float* __restrict__ hs, const float* __restrict__ enc,
    const float* __restrict__ Wq, const float* __restrict__ Wout,
    const float* __restrict__ Wk, const float* __restrict__ Wv,
    const float* __restrict__ Wkip, const float* __restrict__ Wvip,
    ushort* __restrict__ hs_bf, ushort* __restrict__ enc_bf,
    ushort* __restrict__ wqt, ushort* __restrict__ woutt, ushort* __restrict__ wcat,
    float* __restrict__ tip)
{
  __shared__ float tile[32][33];
  int bid = blockIdx.x;
  int t = threadIdx.x;

  if (bid < 20480){                       // hs f32 -> bf16
    int i = bid*256 + t;
    f32x4 v = reinterpret_cast<const f32x4*>(hs)[i];
    ushort4 o = make_ushort4(f2b(v.x), f2b(v.y), f2b(v.z), f2b(v.w));
    reinterpret_cast<ushort4*>(hs_bf)[i] = o;
    return;
  }
  bid -= 20480;
  if (bid < 768){                         // enc f32 -> bf16 (pad to 384 rows)
    int i = bid*256 + t;
    f32x4 v = {0.f,0.f,0.f,0.f};
    if (i < 324*2048/4) v = reinterpret_cast<const f32x4*>(enc)[i];
    ushort4 o = make_ushort4(f2b(v.x), f2b(v.y), f2b(v.z), f2b(v.w));
    reinterpret_cast<ushort4*>(enc_bf)[i] = o;
    return;
  }
  bid -= 768;
  if (bid < 13440){                       // weight transposes
    const float* Wsrc; ushort* Wdst; int K;
    if (bid < 1600)      { Wsrc = Wq;   Wdst = wqt;                    K = 1280; }
    else if (bid < 3200) { bid -= 1600; Wsrc = Wout; Wdst = woutt;     K = 1280; }
    else if (bid < 5760) { bid -= 3200; Wsrc = Wk;   Wdst = wcat;      K = 2048; }
    else if (bid < 8320) { bid -= 5760; Wsrc = Wv;   Wdst = wcat + 1ull*1280*2048; K = 2048; }
    else if (bid < 10880){ bid -= 8320; Wsrc = Wkip; Wdst = wcat + 2ull*1280*2048; K = 2048; }
    else                 { bid -= 10880; Wsrc = Wvip; Wdst = wcat + 3ull*1280*2048; K = 2048; }
    int n0 = (bid % 40)*32, k0 = (bid / 40)*32;
    int tx = t & 31, ty = t >> 5;
    for (int i = ty; i < 32; i += 8) tile[i][tx] = Wsrc[(size_t)(k0+i)*1280 + n0+tx];
    __syncthreads();
    for (int i = ty; i < 32; i += 8) Wdst[(size_t)(n0+i)*K + k0+tx] = f2b(tile[tx][i]);
    return;
  }
  bid -= 13440;
  {                                       // tip[b][k][n] = 0.125 * text[b,k]·ip[b,n]
    int b = bid / 77, k = bid % 77;
    int n = t >> 6, l = t & 63;
    const float* text = enc + ((size_t)b*81 + k)*2048;
    const float* ip   = enc + ((size_t)b*81 + 77 + n)*2048;
    float acc = 0.f;
    for (int c = l; c < 2048; c += 64) acc += text[c]*ip[c];
    #pragma unroll
    for (int off = 32; off > 0; off >>= 1) acc += __shfl_xor(acc, off);
    if (l == 0) tip[((size_t)b*77 + k)*4 + n] = acc * 0.125f;
  }
}

// ============ shared 128x128 GEMM body: BK=32, 3-buffer counted-vmcnt pipeline ============
// R7's 68-VGPR variant: per K-step = VMW(4); barrier; stage(kt+2); ds_read; 16 MFMA/wave.
// Loads stay in flight across barriers. 48KB LDS -> 3 blocks/CU.
// `#pragma unroll 1` — K is compile-time const here; full unroll costs +24 VGPR (R9/R10).
// Plain epilogue loads/stores: nontemporal scalar stores defeat L2 write-coalescing
// (R16: WRITE_SIZE 82.5->105.5 MB, +9us) — do NOT use them here.
template<int MODE>
__device__ __forceinline__ void gemm_body(
    const ushort* __restrict__ A, const ushort* __restrict__ Bt,
    int K, int lda, int ldb, int ldo,
    float* __restrict__ outF, ushort* __restrict__ outB,
    const float* __restrict__ bias, const float* __restrict__ resid,
    int mt, int nt)
{
  __shared__ ushort As[3][128*32];
  __shared__ ushort Bs[3][128*32];
  int t = threadIdx.x;
  int w = t >> 6, l = t & 63;
  int wr = w >> 1, wc = w & 1;
  int fr = l & 15, fq = l >> 4;

  int r0 = t >> 2, s0 = t & 3;
  int r1 = r0 + 64;
  int sc0 = ((s0 ^ ((r0 >> 1) & 3)) << 3);
  int sc1 = ((s0 ^ ((r1 >> 1) & 3)) << 3);
  const ushort* Ag0 = A  + (size_t)(mt*128 + r0)*lda + sc0;
  const ushort* Ag1 = A  + (size_t)(mt*128 + r1)*lda + sc1;
  const ushort* Bg0 = Bt + (size_t)(nt*128 + r0)*ldb + sc0;
  const ushort* Bg1 = Bt + (size_t)(nt*128 + r1)*ldb + sc1;

  f32x4 acc[4][4];
  #pragma unroll
  for (int m = 0; m < 4; ++m)
    #pragma unroll
    for (int n = 0; n < 4; ++n) acc[m][n] = (f32x4){0.f,0.f,0.f,0.f};

  auto stage = [&](int s, int kt){
    int ko = kt << 5;
    ushort* a = &As[s][0] + t*8;
    ushort* b = &Bs[s][0] + t*8;
    gload16(Ag0 + ko, a);
    gload16(Ag1 + ko, a + 2048);
    gload16(Bg0 + ko, b);
    gload16(Bg1 + ko, b + 2048);
  };
  auto compute = [&](int s){
    bf16x8 af[4], bf[4];
    #pragma unroll
    for (int m = 0; m < 4; ++m){
      int row = wr*64 + m*16 + fr;
      af[m] = *reinterpret_cast<const bf16x8*>(&As[s][row*32 + ((fq ^ ((row >> 1) & 3)) << 3)]);
    }
    #pragma unroll
    for (int n = 0; n < 4; ++n){
      int row = wc*64 + n*16 + fr;
      bf[n] = *reinterpret_cast<const bf16x8*>(&Bs[s][row*32 + ((fq ^ ((row >> 1) & 3)) << 3)]);
    }
    #pragma unroll
    for (int m = 0; m < 4; ++m)
      #pragma unroll
      for (int n = 0; n < 4; ++n)
        acc[m][n] = __builtin_amdgcn_mfma_f32_16x16x32_bf16(af[m], bf[n], acc[m][n], 0, 0, 0);
  };

  int nk = K >> 5;
  stage(0, 0);
  stage(1, 1);
  int kt = 0;
  #pragma unroll 1
  for (; kt < nk - 1; ++kt){
    VMW(4);                 // tile kt landed (only stage(kt+1) may be in flight)
    BARR;
    if (kt + 2 < nk) stage((kt + 2) % 3, kt + 2);
    compute(kt % 3);
  }
  VMW(0);
  BARR;
  compute(kt % 3);

  int fqb = fq << 2;
  #pragma unroll
  for (int m = 0; m < 4; ++m){
    #pragma unroll
    for (int n = 0; n < 4; ++n){
      #pragma unroll
      for (int r = 0; r < 4; ++r){
        int row = mt*128 + wr*64 + m*16 + fqb + r;
        int col = nt*128 + wc*64 + n*16 + fr;
        size_t oidx = (size_t)row*ldo + col;
        float v = acc[m][n][r];
        if (MODE == 0) outB[oidx] = f2b(v);
        else           outF[oidx] = v + bias[col] + resid[oidx];
      }
    }
  }
}

// enc-proj (K=2048, longer blocks) on blockIdx 0..119 so they launch FIRST and run
// in q-proj's shadow; q-proj swizzled bijectively over its own 1280 range.
__global__ __launch_bounds__(256) void gemm_dual_k(
    const ushort* __restrict__ A1, const ushort* __restrict__ B1, ushort* __restrict__ O1,
    const ushort* __restrict__ A2, const ushort* __restrict__ B2, ushort* __restrict__ O2)
{
  int bid = blockIdx.x;
  if (bid < 120){
    gemm_body<0>(A2, B2, 2048, 2048, 2048, 5120,
                 nullptr, O2, nullptr, nullptr, bid/40, bid%40);
  } else {
    int qb = bid - 120;
    qb = (qb & 7)*160 + (qb >> 3);        // 1280/8 = 160, bijective
    gemm_body<0>(A1, B1, 1280, 1280, 1280, 1280,
                 nullptr, O1, nullptr, nullptr, qb/10, qb%10);
  }
}

// out-proj: fp32 + bias + residual
__global__ __launch_bounds__(256) void gemm_out_k(
    const ushort* __restrict__ A, const ushort* __restrict__ Bt, float* __restrict__ outF,
    const float* __restrict__ bias, const float* __restrict__ resid)
{
  int nwg = gridDim.x;
  int bid = blockIdx.x;
  if ((nwg & 7) == 0){
    int cpx = nwg >> 3;
    bid = (bid & 7)*cpx + (bid >> 3);
  }
  gemm_body<1>(A, Bt, 1280, 1280, 1280, 1280,
               outF, nullptr, bias, resid, bid/10, bid%10);
}

// ============ fused logits + text-softmax + sem kernel ============
__global__ __launch_bounds__(256) void logits_sem_k(
    const ushort* __restrict__ q, const ushort* __restrict__ pall,
    const float* __restrict__ tip, float* __restrict__ sem)
{
  __shared__ ushort As[64][40];
  __shared__ ushort Bs[128][40];
  __shared__ float tipS[77][4];
  int mt = blockIdx.x;
  int z  = blockIdx.z;
  int t = threadIdx.x;
  const ushort* Ab = q + (size_t)z*4096*1280;
  const ushort* Bb = pall + (size_t)z*81*5120;
  for (int i = t; i < 308; i += 256) (&tipS[0][0])[i] = tip[(size_t)z*308 + i];

  int w = t >> 6, l = t & 63;
  int fr = l & 15, fq = l >> 4, fk = fq << 3;
  int alr = t >> 2, alc = (t & 3) << 3;

  const ushort* Aptr  = Ab + (size_t)(mt*64 + alr)*1280 + alc;
  const ushort* Bptr0 = Bb + (size_t)alr*5120 + alc;
  const ushort* Bptr1 = Bb + (size_t)(64 + alr)*5120 + alc;

  f32x4 acc[5];
  #pragma unroll
  for (int n = 0; n < 5; ++n) acc[n] = (f32x4){0.f,0.f,0.f,0.f};

  uint4 a0 = *reinterpret_cast<const uint4*>(Aptr);
  uint4 b0 = *reinterpret_cast<const uint4*>(Bptr0);
  uint4 b1 = *reinterpret_cast<const uint4*>(Bptr1);
  #pragma unroll 1
  for (int k0 = 0; k0 < 1280; k0 += 32){
    __syncthreads();
    *reinterpret_cast<uint4*>(&As[alr][alc]) = a0;
    *reinterpret_cast<uint4*>(&Bs[alr][alc]) = b0;
    *reinterpret_cast<uint4*>(&Bs[64+alr][alc]) = b1;
    if (k0 + 32 < 1280){
      a0 = *reinterpret_cast<const uint4*>(Aptr + k0 + 32);
      b0 = *reinterpret_cast<const uint4*>(Bptr0 + k0 + 32);
      b1 = *reinterpret_cast<const uint4*>(Bptr1 + k0 + 32);
    }
    __syncthreads();
    bf16x8 af = *reinterpret_cast<const bf16x8*>(&As[w*16 + fr][fk]);
    #pragma unroll
    for (int n = 0; n < 5; ++n){
      bf16x8 bf = *reinterpret_cast<const bf16x8*>(&Bs[n*16 + fr][fk]);
      acc[n] = __builtin_amdgcn_mfma_f32_16x16x32_bf16(af, bf, acc[n], 0, 0, 0);
    }
  }

  bool v4 = (fr < 13);     // col 64+fr < 77
  #pragma unroll
  for (int r = 0; r < 4; ++r){
    float lg[5];
    #pragma unroll
    for (int n = 0; n < 5; ++n) lg[n] = acc[n][r]*0.125f;
    float m = fmaxf(fmaxf(lg[0],lg[1]), fmaxf(lg[2],lg[3]));
    if (v4) m = fmaxf(m, lg[4]);
    #pragma unroll
    for (int off = 1; off < 16; off <<= 1) m = fmaxf(m, __shfl_xor(m, off));
    float s = __expf(lg[0]-m) + __expf(lg[1]-m) + __expf(lg[2]-m) + __expf(lg[3]-m);
    if (v4) s += __expf(lg[4]-m);
    #pragma unroll
    for (int off = 1; off < 16; off <<= 1) s += __shfl_xor(s, off);
    float inv = 1.f / s;
    float a0s = 0.f, a1s = 0.f, a2s = 0.f, a3s = 0.f;
    #pragma unroll
    for (int n = 0; n < 5; ++n){
      int c = n*16 + fr;
      if (n < 4 || v4){
        float p = __expf(lg[n]-m) * inv;
        a0s += p*tipS[c][0]; a1s += p*tipS[c][1];
        a2s += p*tipS[c][2]; a3s += p*tipS[c][3];
      }
    }
    #pragma unroll
    for (int off = 1; off < 16; off <<= 1){
      a0s += __shfl_xor(a0s, off); a1s += __shfl_xor(a1s, off);
      a2s += __shfl_xor(a2s, off); a3s += __shfl_xor(a3s, off);
    }
    if (fr == 0){
      size_t row = (size_t)z*4096 + mt*64 + w*16 + fq*4 + r;
      f32x4 o = {a0s, a1s, a2s, a3s};
      *reinterpret_cast<f32x4*>(&sem[row*4]) = o;
    }
  }
}

// ============ MFMA fused text+ip attention: 4 q-tiles per block ============
// K/V/Vt staged once, amortized over four 64-row Q-tiles (R16: saved ~7-8us vs 2-tile).
__global__ __launch_bounds__(256) void attn_mfma_k(
    const ushort* __restrict__ qb, const ushort* __restrict__ pall,
    const float* __restrict__ sem, const float* __restrict__ mask,
    ushort* __restrict__ hmid)
{
  int qp = blockIdx.x;   // 0..15 (quad of q-tiles)
  int h  = blockIdx.y;   // 0..19
  int b  = blockIdx.z;   // 0..3
  __shared__ ushort Qs[64][72];
  __shared__ ushort Ks[96][72];
  __shared__ ushort Vt[64][104];  // V^T: [d][k]
  __shared__ ushort Ps[64][104];
  int t = threadIdx.x;
  int w = t >> 6, l = t & 63;
  const ushort* pb = pall + (size_t)b*81*5120 + h*64;

  // stage K rows (text 0..76, ip 77..80, zero 81..95)
  #pragma unroll
  for (int it = 0; it < 6; ++it){
    int chunk = t + it*256;
    int k = chunk >> 4, dp = (chunk & 15) << 2;
    ushort4 v = make_ushort4(0,0,0,0);
    if (k < 77)      v = *reinterpret_cast<const ushort4*>(pb + (size_t)k*5120 + dp);
    else if (k < 81) v = *reinterpret_cast<const ushort4*>(pb + (size_t)k*5120 + 2560 + dp);
    *reinterpret_cast<ushort4*>(&Ks[k][dp]) = v;
  }
  // V^T staging (ushort4): rows 81..95 are finite garbage x zero P cols
  #pragma unroll
  for (int it = 0; it < 6; ++it){
    int idx = t + it*256;
    int k = idx >> 4, d4 = (idx & 15) << 2;
    const ushort* src = (k < 77) ? pb + (size_t)k*5120 + 1280 + d4
                                 : pb + (size_t)k*5120 + 3840 + d4;
    ushort4 v = *reinterpret_cast<const ushort4*>(src);
    Vt[d4][k] = v.x; Vt[d4+1][k] = v.y; Vt[d4+2][k] = v.z; Vt[d4+3][k] = v.w;
  }

  int fr = l & 15, fq = l >> 4, fkb = fq << 3;
  int c = fr;

  #pragma unroll 1
  for (int half = 0; half < 4; ++half){
    int qt = qp*4 + half;
    {
      int base = b*4096 + qt*64;
      #pragma unroll
      for (int it = 0; it < 2; ++it){
        int chunk = t + it*256;
        int r = chunk >> 3, dp = (chunk & 7) << 3;
        uint4 v = *reinterpret_cast<const uint4*>(qb + (size_t)(base + r)*1280 + h*64 + dp);
        *reinterpret_cast<uint4*>(&Qs[r][dp]) = v;
      }
    }
    __syncthreads();   // Q (and on half 0: K/V) staged; guards prev-half PV reads of Ps

    f32x4 s[6];
    #pragma unroll
    for (int n = 0; n < 6; ++n) s[n] = (f32x4){0.f,0.f,0.f,0.f};
    #pragma unroll
    for (int ks = 0; ks < 2; ++ks){
      bf16x8 aq = *reinterpret_cast<const bf16x8*>(&Qs[w*16 + fr][ks*32 + fkb]);
      #pragma unroll
      for (int n = 0; n < 6; ++n){
        bf16x8 bk = *reinterpret_cast<const bf16x8*>(&Ks[n*16 + fr][ks*32 + fkb]);
        s[n] = __builtin_amdgcn_mfma_f32_16x16x32_bf16(aq, bk, s[n], 0, 0, 0);
      }
    }

    int rowbase = qt*64 + w*16 + (fq << 2);
    #pragma unroll
    for (int r = 0; r < 4; ++r){
      float lg[6];
      #pragma unroll
      for (int n = 0; n < 6; ++n) lg[n] = s[n][r]*0.125f;

      float mt = fmaxf(fmaxf(lg[0],lg[1]), fmaxf(lg[2],lg[3]));
      if (c < 13) mt = fmaxf(mt, lg[4]);
      #pragma unroll
      for (int off = 1; off < 16; off <<= 1) mt = fmaxf(mt, __shfl_xor(mt, off));
      float st = __expf(lg[0]-mt) + __expf(lg[1]-mt) + __expf(lg[2]-mt) + __expf(lg[3]-mt);
      if (c < 13) st += __expf(lg[4]-mt);
      #pragma unroll
      for (int off = 1; off < 16; off <<= 1) st += __shfl_xor(st, off);
      float invst = 1.f/st;

      size_t qrow = (size_t)b*4096 + rowbase + r;
      float f4 = -1e30f, f5 = -1e30f;
      if (c >= 13) f4 = lg[4] + 0.5f*sem[qrow*4 + (c-13)];
      if (c == 0)  f5 = lg[5] + 0.5f*sem[qrow*4 + 3];
      float m2 = fmaxf(f4, f5);
      #pragma unroll
      for (int off = 1; off < 16; off <<= 1) m2 = fmaxf(m2, __shfl_xor(m2, off));
      float si = (c >= 13 ? __expf(f4-m2) : 0.f) + (c == 0 ? __expf(f5-m2) : 0.f);
      #pragma unroll
      for (int off = 1; off < 16; off <<= 1) si += __shfl_xor(si, off);
      float pmul = mask[rowbase + r] / si;

      int prow = w*16 + (fq << 2) + r;
      #pragma unroll
      for (int n = 0; n < 4; ++n) Ps[prow][n*16 + c] = f2b(__expf(lg[n]-mt)*invst);
      Ps[prow][64 + c] = f2b(c < 13 ? __expf(lg[4]-mt)*invst : __expf(f4-m2)*pmul);
      Ps[prow][80 + c] = f2b(c == 0 ? __expf(f5-m2)*pmul : 0.f);
    }
    __syncthreads();   // Ps complete before PV

    f32x4 o[4];
    #pragma unroll
    for (int df = 0; df < 4; ++df) o[df] = (f32x4){0.f,0.f,0.f,0.f};
    #pragma unroll
    for (int ks = 0; ks < 3; ++ks){
      bf16x8 ap = *reinterpret_cast<const bf16x8*>(&Ps[w*16 + fr][ks*32 + fkb]);
      #pragma unroll
      for (int df = 0; df < 4; ++df){
        bf16x8 bv = *reinterpret_cast<const bf16x8*>(&Vt[df*16 + fr][ks*32 + fkb]);
        o[df] = __builtin_amdgcn_mfma_f32_16x16x32_bf16(ap, bv, o[df], 0, 0, 0);
      }
    }
    #pragma unroll
    for (int df = 0; df < 4; ++df)
      #pragma unroll
      for (int r = 0; r < 4; ++r)
        hmid[((size_t)b*4096 + rowbase + r)*1280 + h*64 + df*16 + c] = f2b(o[df][r]);
  }
}

extern "C" void kernel_launch(void* const* d_in, const int* in_sizes, int n_in,
                              void* d_out, int out_size, void* d_ws, size_t ws_size,
                              hipStream_t stream)
{
  (void)in_sizes; (void)n_in; (void)out_size; (void)ws_size;
  const float* hs   = (const float*)d_in[0];
  const float* enc  = (const float*)d_in[1];
  const float* mask = (const float*)d_in[2];
  const float* Wq   = (const float*)d_in[3];
  const float* Wk   = (const float*)d_in[4];
  const float* Wv   = (const float*)d_in[5];
  const float* Wkip = (const float*)d_in[6];
  const float* Wvip = (const float*)d_in[7];
  const float* Wout = (const float*)d_in[8];
  const float* bout = (const float*)d_in[9];
  float* out = (float*)d_out;
  char* ws = (char*)d_ws;

  size_t off = 0;
  auto alloc = [&](size_t bytes)->char*{
    char* p = ws + off; off += (bytes + 255) & ~(size_t)255; return p;
  };
  ushort* hs_bf   = (ushort*)alloc(16384ull*1280*2);   // reused as hmid
  ushort* q_bf    = (ushort*)alloc(16384ull*1280*2);
  ushort* enc_bf  = (ushort*)alloc(384ull*2048*2);
  ushort* wqt     = (ushort*)alloc(1280ull*1280*2);
  ushort* woutt   = (ushort*)alloc(1280ull*1280*2);
  ushort* wcat    = (ushort*)alloc(5120ull*2048*2);
  ushort* pall    = (ushort*)alloc(384ull*5120*2);
  float*  tip     = (float*)alloc(4ull*77*4*4);
  float*  semb    = (float*)alloc(16384ull*4*4);
  ushort* hmid_bf = hs_bf;

  // 1) all preprocessing in one launch
  prep_k<<<34996, 256, 0, stream>>>(hs, enc, Wq, Wout, Wk, Wv, Wkip, Wvip,
                                    hs_bf, enc_bf, wqt, woutt, wcat, tip);

  // 2) q-projection + encoder projections in one launch (enc first)
  gemm_dual_k<<<1400, 256, 0, stream>>>(hs_bf, wqt, q_bf, enc_bf, wcat, pall);

  // 3) fused logits + text softmax + sem
  logits_sem_k<<<dim3(64,1,4), 256, 0, stream>>>(q_bf, pall, tip, semb);

  // 4) fused attention -> hmid (bf16)
  attn_mfma_k<<<dim3(16,20,4), 256, 0, stream>>>(q_bf, pall, semb, mask, hmid_bf);

  // 5) out = hmid @ Wout + bout + residual
  gemm_out_k<<<1280, 256, 0, stream>>>(hmid_bf, woutt, out, bout, hs);
}